// Round 5
// baseline (126.077 us; speedup 1.0000x reference)
//
#include <hip/hip_runtime.h>
#include <hip/hip_bf16.h>

#define B_ 2
#define N_ 512
#define D_ 64
#define H_ 128
#define OUT_ 64
#define NPAIRS_F 262144.0f   // N_*N_

using bf16x8 = __attribute__((ext_vector_type(8))) __bf16;
using f32x4  = __attribute__((ext_vector_type(4))) float;
using f32x2  = __attribute__((ext_vector_type(2))) float;

// ws layout (bytes):
//   xa_b1 : float[B*N*H]          @ 0        (524288)
//   xb    : float[B*N*H]          @ 524288   (524288)
//   w2t   : bf16 [H*H]            @ 1048576  (32768)
//   S     : float[B*H]            @ 1081344  (1024)
//   cnt   : uint                  @ 1082368  (4)

__global__ __launch_bounds__(256) void prep_kernel(
    const float* __restrict__ x, const float* __restrict__ W1,
    const float* __restrict__ b1, const float* __restrict__ W2,
    float* __restrict__ xa, float* __restrict__ xb,
    __hip_bfloat16* __restrict__ w2t, float* __restrict__ S,
    unsigned int* __restrict__ cnt)
{
    int idx = blockIdx.x * 256 + threadIdx.x;
    if (idx < B_ * N_ * H_) {
        int h  = idx & (H_ - 1);
        int bn = idx >> 7;                 // b*N + n
        const float* xr = x + bn * D_;
        float aa = 0.f, ab = 0.f;
        #pragma unroll
        for (int k = 0; k < D_; k++) {
            float xv = xr[k];
            aa += xv * W1[k * H_ + h];
            ab += xv * W1[(k + D_) * H_ + h];
        }
        xa[idx] = aa + b1[h];              // fold b1 into xa
        xb[idx] = ab;
    }
    if (idx < H_ * H_) {                   // W2 transposed, bf16
        int k = idx & (H_ - 1);
        int n = idx >> 7;
        w2t[n * H_ + k] = __float2bfloat16(W2[k * H_ + n]);
    }
    if (idx < B_ * H_) S[idx] = 0.f;
    if (idx == 0) *cnt = 0u;
}

// Block: 256 threads (4 waves). Tile: 64 i's x 16 j's. Wave w handles i's
// [i0+16w, i0+16w+16), each i is one 16-row MFMA tile (rows = 16 j's).
// W2^T fragments live in registers for the whole block (reused 64x).
// xb rows for the block's 64 i's are staged in LDS once (32 KB).
// Epilogue uses relu(acc+b2) = max(acc,-b2)+b2; the linear +N^2*b2 term
// is re-added in the fused tail (S_true = S + N^2*b2).
//
// Fused tail ordering (R1 passed w/ full threadfence; R4 failed w/o any):
//   - every wave that issued S atomics executes a RELEASE-only agent fence
//     (s_waitcnt vmcnt(0) + wbl2, NO L2 invalidate) before the barrier,
//     so all S atomics are at the coherent point before tid0 bumps cnt;
//   - only the WINNER block executes the ACQUIRE agent fence (one
//     buffer_inv in the whole dispatch, not 512 like __threadfence did).
__global__ __launch_bounds__(256, 2) void pair_kernel(
    const float* __restrict__ xa, const float* __restrict__ xb,
    const uint4* __restrict__ w2t, const float* __restrict__ b2,
    float* __restrict__ S, const float* __restrict__ W3,
    const float* __restrict__ b3, const float* __restrict__ V1,
    const float* __restrict__ c1, const float* __restrict__ V2,
    const float* __restrict__ c2, float* __restrict__ out,
    unsigned int* __restrict__ cnt)
{
    const int tid  = threadIdx.x;
    const int lane = tid & 63;
    const int wid  = tid >> 6;
    const int l15  = lane & 15;
    const int quad = lane >> 4;

    const int j0 = blockIdx.x * 16;
    const int i0 = blockIdx.y * 64;
    const int b  = blockIdx.z;

    __shared__ float xbs[64 * H_];         // 32 KB: xb rows i0..i0+64

    // ---- stage xb tile: issue all 8 16B loads first (batched in flight) ----
    const f32x4* xbsrc = (const f32x4*)(xb + ((size_t)(b * N_) + i0) * H_);
    f32x4 stmp[8];
    #pragma unroll
    for (int t = 0; t < 8; t++) stmp[t] = xbsrc[t * 256 + tid];

    // B fragments: bfrag[c][s] = W2^T[16c+l15][32s + 8*quad .. +8]
    bf16x8 bfrag[8][4];
    #pragma unroll
    for (int c = 0; c < 8; c++) {
        int row = 16 * c + l15;
        #pragma unroll
        for (int s = 0; s < 4; s++) {
            union { uint4 u; bf16x8 v; } cv;
            cv.u = w2t[row * 16 + s * 4 + quad];
            bfrag[c][s] = cv.v;
        }
    }

    // xa(+b1) for this block's 16 j's: per lane 32 floats (k = 32s+8quad+t)
    const float* xaB = xa + (size_t)(b * N_ + j0 + l15) * H_;
    f32x4 av[4][2];
    #pragma unroll
    for (int s = 0; s < 4; s++) {
        const f32x4* p = (const f32x4*)(xaB + s * 32 + quad * 8);
        av[s][0] = p[0];
        av[s][1] = p[1];
    }

    // -b2 per column this lane owns (deferred +b2 handled in tail)
    float nb2[8];
    #pragma unroll
    for (int c = 0; c < 8; c++) nb2[c] = -b2[16 * c + l15];

    // ---- write staged xb tile to LDS, then barrier ----
    {
        f32x4* dst = (f32x4*)xbs;
        #pragma unroll
        for (int t = 0; t < 8; t++) dst[t * 256 + tid] = stmp[t];
    }
    __syncthreads();

    f32x2 csum[8];
    #pragma unroll
    for (int c = 0; c < 8; c++) { csum[c][0] = 0.f; csum[c][1] = 0.f; }

    const f32x4 zero4 = {0.f, 0.f, 0.f, 0.f};
    const float* xrow = xbs + (wid * 16) * H_;

    #pragma unroll 2
    for (int r = 0; r < 16; r++) {
        const float* xr = xrow + r * H_;

        // A fragments: relu(xa[j0+l15] + xb[i] (+b1)) -> bf16
        bf16x8 afr[4];
        #pragma unroll
        for (int s = 0; s < 4; s++) {
            const f32x4* p = (const f32x4*)(xr + s * 32 + quad * 8);
            f32x4 f0 = av[s][0] + p[0];
            f32x4 f1 = av[s][1] + p[1];
            f0 = __builtin_elementwise_max(f0, zero4);
            f1 = __builtin_elementwise_max(f1, zero4);
            bf16x8 a;
            #pragma unroll
            for (int t = 0; t < 4; t++) {
                a[t]     = (__bf16)f0[t];
                a[t + 4] = (__bf16)f1[t];
            }
            afr[s] = a;
        }

        #pragma unroll
        for (int c = 0; c < 8; c++) {
            f32x4 acc = {0.f, 0.f, 0.f, 0.f};
            #pragma unroll
            for (int s = 0; s < 4; s++)
                acc = __builtin_amdgcn_mfma_f32_16x16x32_bf16(afr[s], bfrag[c][s], acc, 0, 0, 0);
            // sum_rows max(acc, -b2)  (the +b2 per-row term is added in tail)
            f32x2 lo; lo[0] = acc[0]; lo[1] = acc[1];
            f32x2 hi; hi[0] = acc[2]; hi[1] = acc[3];
            f32x2 nb; nb[0] = nb2[c]; nb[1] = nb2[c];
            lo = __builtin_elementwise_max(lo, nb);
            hi = __builtin_elementwise_max(hi, nb);
            csum[c] += lo + hi;
        }
    }

    // cross-quad reduction: every lane ends with full column sum for col 16c+l15
    float redv[8];
    #pragma unroll
    for (int c = 0; c < 8; c++) {
        float v = csum[c][0] + csum[c][1];
        v += __shfl_xor(v, 16, 64);
        v += __shfl_xor(v, 32, 64);
        redv[c] = v;
    }

    __shared__ float sred[4][H_];
    if (lane < 16) {
        #pragma unroll
        for (int c = 0; c < 8; c++) sred[wid][c * 16 + l15] = redv[c];
    }
    __syncthreads();
    if (tid < H_) {
        float tot = sred[0][tid] + sred[1][tid] + sred[2][tid] + sred[3][tid];
        atomicAdd(&S[b * H_ + tid], tot);
    }
    // RELEASE-only agent fence: drain this wave's in-flight S atomics to the
    // coherent point (waitcnt + wbl2; no L2 invalidate). Waves 0,1 are fully
    // active in the tid<H_ branch; fence all waves for uniformity.
    __builtin_amdgcn_fence(__ATOMIC_RELEASE, "agent");

    __shared__ unsigned int lastFlag;
    __syncthreads();
    if (tid == 0) {
        unsigned int total = gridDim.x * gridDim.y * gridDim.z;
        unsigned int prev  = atomicAdd(cnt, 1u);
        lastFlag = (prev == total - 1) ? 1u : 0u;
    }
    __syncthreads();
    if (lastFlag) {
        // ACQUIRE agent fence (winner block only): one buffer_inv total.
        __builtin_amdgcn_fence(__ATOMIC_ACQUIRE, "agent");
        __shared__ float Ss[B_][H_], pool[B_][H_], ov[B_][H_];
        const int tb = tid >> 7;          // 0..1 (batch)
        const int tt = tid & 127;         // 0..127 (h)
        float sv = __hip_atomic_load(&S[tb * H_ + tt], __ATOMIC_RELAXED,
                                     __HIP_MEMORY_SCOPE_AGENT);
        Ss[tb][tt] = sv + NPAIRS_F * b2[tt];   // restore deferred b2 term
        __syncthreads();
        float acc = 0.f;
        #pragma unroll 8
        for (int k = 0; k < H_; k++) acc += Ss[tb][k] * W3[k * H_ + tt];
        pool[tb][tt] = acc + NPAIRS_F * b3[tt];
        __syncthreads();
        acc = c1[tt];
        #pragma unroll 8
        for (int k = 0; k < H_; k++) acc += pool[tb][k] * V1[k * H_ + tt];
        ov[tb][tt] = acc > 0.f ? acc : 0.f;
        __syncthreads();
        if (tt < OUT_) {
            acc = c2[tt];
            #pragma unroll 8
            for (int k = 0; k < H_; k++) acc += ov[tb][k] * V2[k * OUT_ + tt];
            out[tb * OUT_ + tt] = acc;
        }
    }
}

extern "C" void kernel_launch(void* const* d_in, const int* in_sizes, int n_in,
                              void* d_out, int out_size, void* d_ws, size_t ws_size,
                              hipStream_t stream) {
    const float* x  = (const float*)d_in[0];
    const float* W1 = (const float*)d_in[1];
    const float* b1 = (const float*)d_in[2];
    const float* W2 = (const float*)d_in[3];
    const float* b2 = (const float*)d_in[4];
    const float* W3 = (const float*)d_in[5];
    const float* b3 = (const float*)d_in[6];
    const float* V1 = (const float*)d_in[7];
    const float* c1 = (const float*)d_in[8];
    const float* V2 = (const float*)d_in[9];
    const float* c2 = (const float*)d_in[10];
    float* out = (float*)d_out;

    char* ws = (char*)d_ws;
    float*          xa  = (float*)(ws);
    float*          xb  = (float*)(ws + 524288);
    __hip_bfloat16* w2t = (__hip_bfloat16*)(ws + 1048576);
    float*          S   = (float*)(ws + 1048576 + 32768);
    unsigned int*   cnt = (unsigned int*)(ws + 1048576 + 32768 + 1024);

    prep_kernel<<<512, 256, 0, stream>>>(x, W1, b1, W2, xa, xb, w2t, S, cnt);
    dim3 g2(N_ / 16, N_ / 64, B_);
    pair_kernel<<<g2, 256, 0, stream>>>(xa, xb, (const uint4*)w2t, b2, S,
                                        W3, b3, V1, c1, V2, c2, out, cnt);
}

// Round 6
// 113.304 us; speedup vs baseline: 1.1127x; 1.1127x over previous
//
#include <hip/hip_runtime.h>
#include <hip/hip_bf16.h>

#define B_ 2
#define N_ 512
#define D_ 64
#define H_ 128
#define OUT_ 64
#define NPAIRS_F 262144.0f   // N_*N_

using bf16x8 = __attribute__((ext_vector_type(8))) __bf16;
using f32x4  = __attribute__((ext_vector_type(4))) float;
using f32x2  = __attribute__((ext_vector_type(2))) float;

// ws layout (bytes):
//   P : float[B*H][256]  @ 0   (262144)  per-block partial sums (plain stores,
//                                         no atomics, no zero-init needed)

__device__ __forceinline__ bf16x8 pack_bf16x8(f32x4 u0, f32x4 u1) {
    bf16x8 a;
    #pragma unroll
    for (int t = 0; t < 4; t++) { a[t] = (__bf16)u0[t]; a[t + 4] = (__bf16)u1[t]; }
    return a;
}

// ONE fused kernel for prep+pair (no inter-block dependency -> no fences):
// each block recomputes its own xa (16 j-rows) and xb (64 i-rows) tiles from
// x and W1 via MFMA (bf16 inputs, f32 accum), writes them to LDS, then runs
// the R3 inner loop unchanged. Per-block redundancy: 80 MFMAs + ~420
// L2-resident scalar loads (~1-2us) vs ~17us saved by killing the prep
// dispatch + its launch gap + the xa/xb HBM round-trip.
// Epilogue: relu(acc+b2) = max(acc,-b2)+b2; linear +N^2*b2 term re-added in
// tail. Block partials go to P[b*H+h][blk] (plain stores; tail reduces).
__global__ __launch_bounds__(256, 2) void pair_kernel(
    const float* __restrict__ x, const float* __restrict__ W1,
    const float* __restrict__ b1, const float* __restrict__ W2,
    const float* __restrict__ b2, float* __restrict__ P)
{
    const int tid  = threadIdx.x;
    const int lane = tid & 63;
    const int wid  = tid >> 6;
    const int l15  = lane & 15;
    const int quad = lane >> 4;

    const int j0 = blockIdx.x * 16;
    const int i0 = blockIdx.y * 64;
    const int b  = blockIdx.z;

    __shared__ float xbs[64 * H_];       // 32 KB  xb rows i0..i0+64 (stride 128)
    __shared__ float xas[16 * 132];      // 8.25 KB xa rows j0..j0+16 (stride 132, pad)
    __shared__ float sred[4][H_];        // 2 KB

    const f32x4 zero4 = {0.f, 0.f, 0.f, 0.f};

    // ---- Phase A: x fragments (A-operands), bf16 ----
    // x_i: this wave's 16 i-rows; x_j: the block's 16 j-rows. k = s2*32+quad*8+t
    const float* xiB = x + ((size_t)(b * N_) + i0 + wid * 16 + l15) * D_;
    const float* xjB = x + ((size_t)(b * N_) + j0 + l15) * D_;
    bf16x8 Ai[2], Aj[2];
    #pragma unroll
    for (int s2 = 0; s2 < 2; s2++) {
        const f32x4* pi = (const f32x4*)(xiB + s2 * 32 + quad * 8);
        const f32x4* pj = (const f32x4*)(xjB + s2 * 32 + quad * 8);
        Ai[s2] = pack_bf16x8(pi[0], pi[1]);
        Aj[s2] = pack_bf16x8(pj[0], pj[1]);
    }

    // ---- Phase B: W1 fragments (B-operands), bf16 ----
    // B[k][n]: lane l15 = n, k = s2*32+quad*8+t.
    // xb uses W1b = W1[64+k][:], all 8 col-tiles; xa uses W1a = W1[k][:],
    // only this wave's 2 col-tiles (xa cols split across waves).
    bf16x8 Bb[8][2];
    #pragma unroll
    for (int ct = 0; ct < 8; ct++) {
        #pragma unroll
        for (int s2 = 0; s2 < 2; s2++) {
            f32x4 u0, u1;
            #pragma unroll
            for (int t = 0; t < 4; t++) {
                u0[t] = W1[(64 + s2 * 32 + quad * 8 + t) * H_ + ct * 16 + l15];
                u1[t] = W1[(64 + s2 * 32 + quad * 8 + 4 + t) * H_ + ct * 16 + l15];
            }
            Bb[ct][s2] = pack_bf16x8(u0, u1);
        }
    }
    bf16x8 Ba[2][2];
    #pragma unroll
    for (int e = 0; e < 2; e++) {
        int ct = 2 * wid + e;
        #pragma unroll
        for (int s2 = 0; s2 < 2; s2++) {
            f32x4 u0, u1;
            #pragma unroll
            for (int t = 0; t < 4; t++) {
                u0[t] = W1[(s2 * 32 + quad * 8 + t) * H_ + ct * 16 + l15];
                u1[t] = W1[(s2 * 32 + quad * 8 + 4 + t) * H_ + ct * 16 + l15];
            }
            Ba[e][s2] = pack_bf16x8(u0, u1);
        }
    }

    // ---- Phase C: MFMA xa/xb tiles -> LDS ----
    // D layout (16x16): col = l15, row = quad*4 + reg.
    #pragma unroll
    for (int ct = 0; ct < 8; ct++) {
        f32x4 acc = zero4;
        acc = __builtin_amdgcn_mfma_f32_16x16x32_bf16(Ai[0], Bb[ct][0], acc, 0, 0, 0);
        acc = __builtin_amdgcn_mfma_f32_16x16x32_bf16(Ai[1], Bb[ct][1], acc, 0, 0, 0);
        #pragma unroll
        for (int reg = 0; reg < 4; reg++)
            xbs[(wid * 16 + quad * 4 + reg) * H_ + ct * 16 + l15] = acc[reg];
    }
    #pragma unroll
    for (int e = 0; e < 2; e++) {
        int ct = 2 * wid + e;
        f32x4 acc = zero4;
        acc = __builtin_amdgcn_mfma_f32_16x16x32_bf16(Aj[0], Ba[e][0], acc, 0, 0, 0);
        acc = __builtin_amdgcn_mfma_f32_16x16x32_bf16(Aj[1], Ba[e][1], acc, 0, 0, 0);
        float bv = b1[ct * 16 + l15];
        #pragma unroll
        for (int reg = 0; reg < 4; reg++)
            xas[(quad * 4 + reg) * 132 + ct * 16 + l15] = acc[reg] + bv;
    }

    // Keep Bb/Ba/Ai/Aj dead before the 128-VGPR bfrag set goes live.
    __builtin_amdgcn_sched_barrier(0);

    // ---- Phase D: W2 B-fragments (held in registers for the whole loop) ----
    // bfrag[c][s] lane value = W2[k = 32s+8quad+t][n = 16c+l15]
    bf16x8 bfrag[8][4];
    #pragma unroll
    for (int c = 0; c < 8; c++) {
        #pragma unroll
        for (int s = 0; s < 4; s++) {
            f32x4 u0, u1;
            #pragma unroll
            for (int t = 0; t < 4; t++) {
                u0[t] = W2[(s * 32 + quad * 8 + t) * H_ + c * 16 + l15];
                u1[t] = W2[(s * 32 + quad * 8 + 4 + t) * H_ + c * 16 + l15];
            }
            bfrag[c][s] = pack_bf16x8(u0, u1);
        }
    }

    // -b2 per column this lane owns (deferred +b2 handled in tail)
    float nb2[8];
    #pragma unroll
    for (int c = 0; c < 8; c++) nb2[c] = -b2[16 * c + l15];

    __syncthreads();                      // xas/xbs visible

    // ---- Phase E: xa(+b1) row for this lane's j, from LDS ----
    f32x4 av[4][2];
    #pragma unroll
    for (int s = 0; s < 4; s++) {
        const f32x4* p = (const f32x4*)(xas + l15 * 132 + s * 32 + quad * 8);
        av[s][0] = p[0];
        av[s][1] = p[1];
    }

    f32x2 csum[8];
    #pragma unroll
    for (int c = 0; c < 8; c++) { csum[c][0] = 0.f; csum[c][1] = 0.f; }

    const float* xrow = xbs + (wid * 16) * H_;

    // ---- main loop: identical to R3 ----
    #pragma unroll 2
    for (int r = 0; r < 16; r++) {
        const float* xr = xrow + r * H_;

        bf16x8 afr[4];
        #pragma unroll
        for (int s = 0; s < 4; s++) {
            const f32x4* p = (const f32x4*)(xr + s * 32 + quad * 8);
            f32x4 f0 = av[s][0] + p[0];
            f32x4 f1 = av[s][1] + p[1];
            f0 = __builtin_elementwise_max(f0, zero4);
            f1 = __builtin_elementwise_max(f1, zero4);
            afr[s] = pack_bf16x8(f0, f1);
        }

        #pragma unroll
        for (int c = 0; c < 8; c++) {
            f32x4 acc = zero4;
            #pragma unroll
            for (int s = 0; s < 4; s++)
                acc = __builtin_amdgcn_mfma_f32_16x16x32_bf16(afr[s], bfrag[c][s], acc, 0, 0, 0);
            f32x2 lo; lo[0] = acc[0]; lo[1] = acc[1];
            f32x2 hi; hi[0] = acc[2]; hi[1] = acc[3];
            f32x2 nb; nb[0] = nb2[c]; nb[1] = nb2[c];
            lo = __builtin_elementwise_max(lo, nb);
            hi = __builtin_elementwise_max(hi, nb);
            csum[c] += lo + hi;
        }
    }

    // cross-quad reduction: full column sum for col 16c+l15
    float redv[8];
    #pragma unroll
    for (int c = 0; c < 8; c++) {
        float v = csum[c][0] + csum[c][1];
        v += __shfl_xor(v, 16, 64);
        v += __shfl_xor(v, 32, 64);
        redv[c] = v;
    }

    if (lane < 16) {
        #pragma unroll
        for (int c = 0; c < 8; c++) sred[wid][c * 16 + l15] = redv[c];
    }
    __syncthreads();
    if (tid < H_) {
        float tot = sred[0][tid] + sred[1][tid] + sred[2][tid] + sred[3][tid];
        int id = blockIdx.x * 8 + blockIdx.y;          // 0..255 within batch
        P[((size_t)(b * H_ + tid)) * 256 + id] = tot;  // plain store, no atomic
    }
}

__global__ __launch_bounds__(128) void tail_kernel(
    const float* __restrict__ P, const float* __restrict__ b2,
    const float* __restrict__ W3, const float* __restrict__ b3,
    const float* __restrict__ V1, const float* __restrict__ c1,
    const float* __restrict__ V2, const float* __restrict__ c2,
    float* __restrict__ out)
{
    __shared__ float Ss[H_], pool[H_], ov[H_];
    const int b = blockIdx.x, t = threadIdx.x;
    // reduce 256 per-block partials for this (b, h)
    const f32x4* Pr = (const f32x4*)(P + ((size_t)(b * H_ + t)) * 256);
    f32x4 s4 = {0.f, 0.f, 0.f, 0.f};
    #pragma unroll 8
    for (int k = 0; k < 64; k++) s4 += Pr[k];
    // restore the deferred N^2 * b2 term before applying W3
    Ss[t] = (s4[0] + s4[1] + s4[2] + s4[3]) + NPAIRS_F * b2[t];
    __syncthreads();
    float acc = 0.f;
    for (int k = 0; k < H_; k++) acc += Ss[k] * W3[k * H_ + t];
    pool[t] = acc + NPAIRS_F * b3[t];
    __syncthreads();
    acc = c1[t];
    for (int k = 0; k < H_; k++) acc += pool[k] * V1[k * H_ + t];
    ov[t] = acc > 0.f ? acc : 0.f;
    __syncthreads();
    if (t < OUT_) {
        acc = c2[t];
        for (int k = 0; k < H_; k++) acc += ov[k] * V2[k * OUT_ + t];
        out[b * OUT_ + t] = acc;
    }
}

extern "C" void kernel_launch(void* const* d_in, const int* in_sizes, int n_in,
                              void* d_out, int out_size, void* d_ws, size_t ws_size,
                              hipStream_t stream) {
    const float* x  = (const float*)d_in[0];
    const float* W1 = (const float*)d_in[1];
    const float* b1 = (const float*)d_in[2];
    const float* W2 = (const float*)d_in[3];
    const float* b2 = (const float*)d_in[4];
    const float* W3 = (const float*)d_in[5];
    const float* b3 = (const float*)d_in[6];
    const float* V1 = (const float*)d_in[7];
    const float* c1 = (const float*)d_in[8];
    const float* V2 = (const float*)d_in[9];
    const float* c2 = (const float*)d_in[10];
    float* out = (float*)d_out;

    float* P = (float*)d_ws;   // [B*H][256] partials

    dim3 g2(N_ / 16, N_ / 64, B_);
    pair_kernel<<<g2, 256, 0, stream>>>(x, W1, b1, W2, b2, P);
    tail_kernel<<<B_, 128, 0, stream>>>(P, b2, W3, b3, V1, c1, V2, c2, out);
}